// Round 3
// baseline (263.689 us; speedup 1.0000x reference)
//
#include <hip/hip_runtime.h>
#include <stdint.h>

// ---------------- problem constants ----------------
#define BB 4
#define RR 4
#define NN 4096
#define MM 64
#define KK 3
#define KNN 12288           // KK*NN
#define BRR 16              // BB*RR
#define FF 512

typedef short bf16x8 __attribute__((ext_vector_type(8)));
typedef float f32x4 __attribute__((ext_vector_type(4)));

__device__ __forceinline__ float bf2f(unsigned int u) {
  union { unsigned int i; float f; } v; v.i = u << 16; return v.f;
}
__device__ __forceinline__ unsigned short f2bf(float f) {
  union { float f; unsigned int i; } v; v.f = f;
  unsigned int x = v.i;
  return (unsigned short)((x + 0x7fffu + ((x >> 16) & 1u)) >> 16);
}
// packed RNE f32x2 -> bf16x2 (T12 recipe; no builtin on gfx950)
__device__ __forceinline__ unsigned int cvtpk(float a, float b) {
  unsigned int r;
  asm("v_cvt_pk_bf16_f32 %0, %1, %2" : "=v"(r) : "v"(a), "v"(b));
  return r;
}
// dtype-adaptive load: isbf=1 -> buffer is bf16 ushorts; else fp32 floats
__device__ __forceinline__ float ldf(const void* p, long i, int isbf) {
  if (isbf) return bf2f(((const unsigned short*)p)[i]);
  return ((const float*)p)[i];
}
// LDS bank-conflict swizzles for k_fused tiles.
__device__ __forceinline__ int hsw(int col, int so) { return col * 72  + (so ^ (col & 24)); }
__device__ __forceinline__ int csw(int col, int so) { return col * 136 + (so ^ (col & 24)); } // so < 128 only!

struct WPtrs { const void* p[7]; };  // fpW1,fpW2,fpW3,gpW0,gpW1,gpW2,gpW3

// ---------------- K0: merged dtype-probe + weight-cvt + assign ----------------
__global__ __launch_bounds__(256) void k_front(
    const void* __restrict__ x, const void* __restrict__ node, WPtrs wp,
    int* __restrict__ flag, unsigned short* __restrict__ Wb,
    int* __restrict__ idx, float* __restrict__ csum, int* __restrict__ blkcnt) {
  __shared__ int bad;
  __shared__ float nd[2][64];
  __shared__ float cs[192];   // [m][{sx,sy,cnt}]
  int tid = threadIdx.x;
  if (tid == 0) bad = 0;
  __syncthreads();
  {
    const unsigned short* xs = (const unsigned short*)x;
    int cnt = 0;
    for (int i = tid; i < 1024; i += 256) {
      unsigned short u = xs[i * 2];
      int e = (u >> 7) & 0xFF;
      if (e >= 0x90 || (e > 0 && e <= 0x50)) ++cnt;
    }
    atomicAdd(&bad, cnt);
  }
  __syncthreads();
  int isbf = (bad < 100) ? 1 : 0;
  if (blockIdx.x == 0 && tid == 0) flag[0] = isbf;

  if (blockIdx.x < 2295) {
    // ---- weight conversion ----
    const int e0=4096, e1=12288, e2=28928, e3=62208, e4=127744, e5=258816, e6=587520;
    int t = blockIdx.x * 256 + tid;
    if (t >= e6) return;
    int s, base;
    if      (t < e0) { s=0; base=0;  }
    else if (t < e1) { s=1; base=e0; }
    else if (t < e2) { s=2; base=e1; }
    else if (t < e3) { s=3; base=e2; }
    else if (t < e4) { s=4; base=e3; }
    else if (t < e5) { s=5; base=e4; }
    else             { s=6; base=e5; }
    int local = t - base;
    unsigned short u;
    if (isbf) u = ((const unsigned short*)wp.p[s])[local];
    else      u = f2bf(((const float*)wp.p[s])[local]);
    Wb[t] = u;
    return;
  }
  // ---- assign ----
  int bi = blockIdx.x - 2295;        // b*16 + chunk
  int b = bi >> 4;
  int n = ((bi & 15) << 8) + tid;
  if (tid < 128) nd[tid >> 6][tid & 63] = ldf(node, b * 128 + tid, isbf);
  if (tid < 192) cs[tid] = 0.f;
  __syncthreads();
  float x0 = ldf(x, b * 8192 + n, isbf);
  float x1 = ldf(x, b * 8192 + 4096 + n, isbf);
  float d0 = 1e30f, d1 = 1e30f, d2 = 1e30f;
  int m0 = 0, m1 = 0, m2 = 0;
#pragma unroll 8
  for (int m = 0; m < 64; ++m) {
    float dx = x0 - nd[0][m];
    float dy = x1 - nd[1][m];
    float d = __fmul_rn(dx, dx) + __fmul_rn(dy, dy);   // no contraction: match ref
    if (d < d0)      { d2=d1; m2=m1; d1=d0; m1=m0; d0=d; m0=m; }
    else if (d < d1) { d2=d1; m2=m1; d1=d;  m1=m; }
    else if (d < d2) { d2=d;  m2=m; }
  }
  long base = ((long)b * NN + n) * 3;
  idx[base] = m0; idx[base + 1] = m1; idx[base + 2] = m2;
  atomicAdd(&cs[m0*3+0], x0); atomicAdd(&cs[m0*3+1], x1); atomicAdd(&cs[m0*3+2], 1.f);
  atomicAdd(&cs[m1*3+0], x0); atomicAdd(&cs[m1*3+1], x1); atomicAdd(&cs[m1*3+2], 1.f);
  atomicAdd(&cs[m2*3+0], x0); atomicAdd(&cs[m2*3+1], x1); atomicAdd(&cs[m2*3+2], 1.f);
  __syncthreads();
  if (tid < 192) atomicAdd(&csum[b * 192 + tid], cs[tid]);
  if (tid < 64) blkcnt[bi * 64 + tid] = (int)cs[tid*3 + 2];
}

// ---------------- K1: merged means + counting-sort scatter ----------------
__global__ __launch_bounds__(256) void k_scatter2(
    const float* __restrict__ csum, const int* __restrict__ blkcnt,
    const int* __restrict__ idx, int* __restrict__ sorted,
    float* __restrict__ noderot, int* __restrict__ rowflag) {
  __shared__ int scnt[64];
  __shared__ int soff[64];
  __shared__ int lc[64];
  int tid = threadIdx.x;
  int blk = blockIdx.x;              // b*16 + chunk (matches k_front assign)
  int b = blk >> 4, chunk = blk & 15;
  if (tid < 64) scnt[tid] = (int)csum[b*192 + tid*3 + 2];
  __syncthreads();
  if (tid < 64) {
    int m = tid, acc = 0;
    for (int mm = 0; mm < m; ++mm) acc += scnt[mm];          // counts are exact floats
    for (int c = 0; c < chunk; ++c) acc += blkcnt[(b*16 + c)*64 + m];
    soff[m] = acc;
    lc[m] = 0;
    if (chunk == 0) {
      float s0 = csum[b*192 + m*3], s1 = csum[b*192 + m*3 + 1], cc = csum[b*192 + m*3 + 2];
      float mx = s0 / (cc + 1e-5f);
      float my = s1 / (cc + 1e-5f);
      rowflag[b*64 + m] = (cc > 0.f) ? 1 : 0;
      for (int r = 0; r < 4; ++r) {
        float th = 1.5707964f * (float)r;
        float cr = cosf(th), sr = sinf(th);
        noderot[((b*4 + r)*2 + 0)*64 + m] = cr*mx - sr*my;
        noderot[((b*4 + r)*2 + 1)*64 + m] = sr*mx + cr*my;
      }
    }
  }
  __syncthreads();
  int n = ((blk & 15) << 8) + tid;
#pragma unroll
  for (int kk = 0; kk < 3; ++kk) {
    int m = idx[((long)b * NN + n) * 3 + kk];
    int pos = atomicAdd(&lc[m], 1);                 // LDS atomic, order irrelevant
    sorted[b * KNN + soff[m] + pos] = (m << 12) | n;
  }
}

// ---------------- K5: fused fp block, 4 column-tiles per block ----------------
// grid (48, 16): each block processes 4 x 64 m-sorted columns; MFMA weight
// fragments are hoisted to registers ONCE per block (loop-invariant), so the
// per-tile K-loops are pure LDS-read + MFMA (no L2-latency weight loads).
__global__ __launch_bounds__(256) void k_fused(
    const void* __restrict__ x, const int* __restrict__ sorted,
    const int* __restrict__ idx, const float* __restrict__ noderot,
    const int* __restrict__ flag,
    const void* __restrict__ fW0, const void* __restrict__ fb0,
    const unsigned short* __restrict__ Wb,
    const void* __restrict__ fb1, const void* __restrict__ fb2,
    const void* __restrict__ fb3,
    unsigned int* __restrict__ pooled, float* __restrict__ feat0) {
  __shared__ unsigned short Cs[64 * 136];   // [col][0..1]=xdec, [2..129]=h2; later [0..127]=feat
  __shared__ unsigned short Hs[64 * 72];    // h1
  __shared__ int mcol[64];                  // m | (is_col0 << 8)
  const unsigned short* fW1 = Wb;           // 64x64
  const unsigned short* fW2 = Wb + 4096;    // 128x64
  const unsigned short* fW3 = Wb + 12288;   // 128x130
  int isbf = flag[0];
  int tid = threadIdx.x, lane = tid & 63, wv = tid >> 6;
  int quad = lane >> 4, lr = lane & 15;
  int br = blockIdx.y, b = br >> 2, r = br & 3;
  int o1 = wv * 16;
  // ---- hoist MFMA weight fragments (invariant across tiles) ----
  bf16x8 aW1[2], aW2[2][2], aW3[2][4];
  unsigned int tw3[2][4];
#pragma unroll
  for (int ks2 = 0; ks2 < 2; ++ks2)
    aW1[ks2] = *(const bf16x8*)(fW1 + (o1 + lr)*64 + ks2*32 + quad*8);
#pragma unroll
  for (int p2 = 0; p2 < 2; ++p2)
#pragma unroll
    for (int ks2 = 0; ks2 < 2; ++ks2)
      aW2[p2][ks2] = *(const bf16x8*)(fW2 + (p2*64 + o1 + lr)*64 + ks2*32 + quad*8);
#pragma unroll
  for (int p3 = 0; p3 < 2; ++p3) {
#pragma unroll
    for (int ks4 = 0; ks4 < 4; ++ks4) {
      union { bf16x8 v; unsigned int u[4]; } au;
      const unsigned int* ap =
          (const unsigned int*)(fW3 + (long)(p3*64 + o1 + lr)*130 + ks4*32 + quad*8);
      au.u[0] = ap[0]; au.u[1] = ap[1]; au.u[2] = ap[2]; au.u[3] = ap[3];
      aW3[p3][ks4] = au.v;
    }
#pragma unroll
    for (int rr = 0; rr < 4; ++rr)
      tw3[p3][rr] = *(const unsigned int*)(fW3 + (long)(p3*64 + o1 + quad*4 + rr)*130 + 128);
  }

#pragma unroll 1
  for (int t = 0; t < 4; ++t) {
    int xb = (blockIdx.x << 2) + t;
    if (tid < 64) {
      int e = sorted[b * KNN + xb * 64 + tid];
      int m = e >> 12, n = e & 4095;
      int isz = (n == 0 && m == idx[(long)b * NN * 3]) ? 256 : 0;
      mcol[tid] = m | isz;
      float x0 = ldf(x, b*8192 + n, isbf), x1 = ldf(x, b*8192 + 4096 + n, isbf);
      float th = 1.5707964f * (float)r;
      float cr = cosf(th), sr = sinf(th);
      float xd0 = (cr*x0 - sr*x1) - noderot[(br*2 + 0)*64 + m];
      float xd1 = (sr*x0 + cr*x1) - noderot[(br*2 + 1)*64 + m];
      *(unsigned int*)&Cs[csw(tid, 0)] = cvtpk(xd0, xd1);
    }
    __syncthreads();
    // ----- layer0 (2 -> 64), VALU -----
    {
      int col = tid & 63, og = (tid >> 6) << 4;
      unsigned int xu = *(unsigned int*)&Cs[csw(col, 0)];
      float fx0 = bf2f(xu & 0xffff), fx1 = bf2f(xu >> 16);
      float hv[16];
#pragma unroll
      for (int j = 0; j < 16; ++j) {
        int o = og + j;
        float h = ldf(fb0, o, isbf) + ldf(fW0, o*2, isbf) * fx0 + ldf(fW0, o*2+1, isbf) * fx1;
        hv[j] = fmaxf(h, 0.f);
      }
      union { bf16x8 v; unsigned int u[4]; } o8[2];
#pragma unroll
      for (int j = 0; j < 16; j += 2) o8[j >> 3].u[(j & 7) >> 1] = cvtpk(hv[j], hv[j+1]);
      *(bf16x8*)&Hs[hsw(col, og)]     = o8[0].v;
      *(bf16x8*)&Hs[hsw(col, og + 8)] = o8[1].v;
    }
    __syncthreads();
    // ----- layer1 (64 -> 64), MFMA -----
    {
      f32x4 acc[4];
      float bb4[4];
#pragma unroll
      for (int rr = 0; rr < 4; ++rr) bb4[rr] = ldf(fb1, o1 + quad*4 + rr, isbf);
#pragma unroll
      for (int nt = 0; nt < 4; ++nt) acc[nt] = (f32x4){bb4[0], bb4[1], bb4[2], bb4[3]};
#pragma unroll
      for (int ks2 = 0; ks2 < 2; ++ks2) {
#pragma unroll
        for (int nt = 0; nt < 4; ++nt) {
          bf16x8 bf = *(bf16x8*)&Hs[hsw(nt*16 + lr, ks2*32 + quad*8)];
          acc[nt] = __builtin_amdgcn_mfma_f32_16x16x32_bf16(aW1[ks2], bf, acc[nt], 0, 0, 0);
        }
      }
      __syncthreads();  // everyone done READING Hs
#pragma unroll
      for (int nt = 0; nt < 4; ++nt) {
        int col = nt*16 + lr;
        unsigned int lo = cvtpk(fmaxf(acc[nt][0], 0.f), fmaxf(acc[nt][1], 0.f));
        unsigned int hi = cvtpk(fmaxf(acc[nt][2], 0.f), fmaxf(acc[nt][3], 0.f));
        *(unsigned long long*)&Hs[hsw(col, o1 + quad*4)] =
            (unsigned long long)lo | ((unsigned long long)hi << 32);
      }
    }
    __syncthreads();
    // ----- layer2 (64 -> 128), MFMA, output into Cs[2..129] -----
#pragma unroll
    for (int p2 = 0; p2 < 2; ++p2) {
      int o0 = p2*64 + o1;
      f32x4 acc[4];
      float bb4[4];
#pragma unroll
      for (int rr = 0; rr < 4; ++rr) bb4[rr] = ldf(fb2, o0 + quad*4 + rr, isbf);
#pragma unroll
      for (int nt = 0; nt < 4; ++nt) acc[nt] = (f32x4){bb4[0], bb4[1], bb4[2], bb4[3]};
#pragma unroll
      for (int ks2 = 0; ks2 < 2; ++ks2) {
#pragma unroll
        for (int nt = 0; nt < 4; ++nt) {
          bf16x8 bf = *(bf16x8*)&Hs[hsw(nt*16 + lr, ks2*32 + quad*8)];
          acc[nt] = __builtin_amdgcn_mfma_f32_16x16x32_bf16(aW2[p2][ks2], bf, acc[nt], 0, 0, 0);
        }
      }
#pragma unroll
      for (int nt = 0; nt < 4; ++nt) {
        int col = nt*16 + lr;
        int o = o0 + quad*4;
        unsigned int w0 = cvtpk(fmaxf(acc[nt][0], 0.f), fmaxf(acc[nt][1], 0.f));
        unsigned int w1 = cvtpk(fmaxf(acc[nt][2], 0.f), fmaxf(acc[nt][3], 0.f));
        int so0 = 2 + o;                 // < 128 always
        int so1 = 4 + o;                 // == 128 for o == 124 (channels 126,127 -> K tail)
        *(unsigned int*)&Cs[csw(col, so0)] = w0;
        *(unsigned int*)&Cs[(so1 < 128) ? csw(col, so1) : (col*136 + so1)] = w1;
      }
    }
    __syncthreads();
    // ----- layer3 (130 -> 128): both halves in registers, then feats -> Cs[0..127] -----
    f32x4 acc3[2][4];
#pragma unroll
    for (int p3 = 0; p3 < 2; ++p3) {
      int o0 = p3*64 + o1;
      float bb4[4];
#pragma unroll
      for (int rr = 0; rr < 4; ++rr) bb4[rr] = ldf(fb3, o0 + quad*4 + rr, isbf);
#pragma unroll
      for (int nt = 0; nt < 4; ++nt) acc3[p3][nt] = (f32x4){bb4[0], bb4[1], bb4[2], bb4[3]};
#pragma unroll
      for (int ks4 = 0; ks4 < 4; ++ks4) {
#pragma unroll
        for (int nt = 0; nt < 4; ++nt) {
          bf16x8 bf = *(bf16x8*)&Cs[csw(nt*16 + lr, ks4*32 + quad*8)];
          acc3[p3][nt] = __builtin_amdgcn_mfma_f32_16x16x32_bf16(aW3[p3][ks4], bf, acc3[p3][nt], 0, 0, 0);
        }
      }
#pragma unroll
      for (int rr = 0; rr < 4; ++rr) {   // K tail: channels 128..129 (unswizzled shorts 128..129)
        float w0 = bf2f(tw3[p3][rr] & 0xffff), w1 = bf2f(tw3[p3][rr] >> 16);
#pragma unroll
        for (int nt = 0; nt < 4; ++nt) {
          unsigned int bu = *(unsigned int*)&Cs[(nt*16 + lr)*136 + 128];
          acc3[p3][nt][rr] += w0 * bf2f(bu & 0xffff) + w1 * bf2f(bu >> 16);
        }
      }
    }
    __syncthreads();   // ALL Cs reads complete before feat overwrite
#pragma unroll
    for (int p3 = 0; p3 < 2; ++p3) {
      int o0 = p3*64 + o1;
#pragma unroll
      for (int nt = 0; nt < 4; ++nt) {
        int col = nt*16 + lr;
        unsigned int lo = cvtpk(fmaxf(acc3[p3][nt][0], 0.f), fmaxf(acc3[p3][nt][1], 0.f));
        unsigned int hi = cvtpk(fmaxf(acc3[p3][nt][2], 0.f), fmaxf(acc3[p3][nt][3], 0.f));
        *(unsigned long long*)&Cs[csw(col, o0 + quad*4)] =
            (unsigned long long)lo | ((unsigned long long)hi << 32);
      }
    }
    __syncthreads();
    // ----- run-scan segment max -----
    {
      int o = tid & 127, h = tid >> 7;
      int c0 = h * 32;
      int curm = mcol[c0] & 255;
      float v = 0.f;                       // relu'd values >= 0
      for (int c = c0; c < c0 + 32; ++c) {
        int mc = mcol[c];
        int mm = mc & 255;
        float f = bf2f(Cs[csw(c, o)]);
        if (mm != curm) {
          atomicMax(&pooled[(((long)br*64 + curm) << 7) + o], __float_as_uint(v));
          curm = mm; v = 0.f;
        }
        v = fmaxf(v, f);
        if (mc & 256) feat0[br*128 + o] = f;   // (kk=0,n=0) column -> empty-node substitute
      }
      atomicMax(&pooled[(((long)br*64 + curm) << 7) + o], __float_as_uint(v));
    }
    __syncthreads();   // scan reads of Cs/mcol done before next tile's init
  }
}

// ---------------- gp layer helper (per-wave, 16-col n-tile) ----------------
// ot-loop INSIDE ks: one LDS B-read shared by all OT o-tiles, OT independent
// A-loads pipelined per ks step (L2 latency overlapped), OT independent
// MFMA accumulation chains.
template<int OT, int KW, int KMAIN, bool REM2, int DSTR, int DOFF, int EPI>
__device__ __forceinline__ void gp_layer(
    const unsigned short* __restrict__ W, const void* __restrict__ bias, int isbf,
    const unsigned short* Bs, int bstr, unsigned short* Ds,
    int wv, int quad, int lr, int b, unsigned int* __restrict__ outmax) {
  f32x4 acc[OT];
#pragma unroll
  for (int ot = 0; ot < OT; ++ot) {
    int o0 = (wv * OT + ot) * 16;
    float bb4[4];
#pragma unroll
    for (int rr = 0; rr < 4; ++rr) bb4[rr] = ldf(bias, o0 + quad*4 + rr, isbf);
    acc[ot] = (f32x4){bb4[0], bb4[1], bb4[2], bb4[3]};
  }
  const unsigned short* brow = Bs + lr * bstr;
  for (int ks = 0; ks < KMAIN; ks += 32) {
    bf16x8 bf = *(const bf16x8*)(brow + ks + quad*8);
    bf16x8 a[OT];
#pragma unroll
    for (int ot = 0; ot < OT; ++ot) {
      const unsigned short* arow = W + (long)((wv * OT + ot) * 16 + lr) * KW;
      if constexpr ((KW % 8) == 0) {
        a[ot] = *(const bf16x8*)(arow + ks + quad*8);
      } else {
        union { bf16x8 v; unsigned int u[4]; } au;
        const unsigned int* ap = (const unsigned int*)(arow + ks + quad*8);  // 4B aligned
        au.u[0] = ap[0]; au.u[1] = ap[1]; au.u[2] = ap[2]; au.u[3] = ap[3];
        a[ot] = au.v;
      }
    }
#pragma unroll
    for (int ot = 0; ot < OT; ++ot)
      acc[ot] = __builtin_amdgcn_mfma_f32_16x16x32_bf16(a[ot], bf, acc[ot], 0, 0, 0);
  }
  if constexpr (REM2) {
    unsigned int bu = *(const unsigned int*)(brow + KMAIN);
    float b0 = bf2f(bu & 0xffff), b1 = bf2f(bu >> 16);
#pragma unroll
    for (int ot = 0; ot < OT; ++ot) {
#pragma unroll
      for (int rr = 0; rr < 4; ++rr) {
        int o = (wv * OT + ot) * 16 + quad*4 + rr;
        unsigned int wu = *(const unsigned int*)(W + (long)o * KW + KMAIN);
        acc[ot][rr] += bf2f(wu & 0xffff) * b0 + bf2f(wu >> 16) * b1;
      }
    }
  }
#pragma unroll
  for (int ot = 0; ot < OT; ++ot) {
    int o0 = (wv * OT + ot) * 16;
    if constexpr (EPI == 0) {
      unsigned int lo = cvtpk(fmaxf(acc[ot][0], 0.f), fmaxf(acc[ot][1], 0.f));
      unsigned int hi = cvtpk(fmaxf(acc[ot][2], 0.f), fmaxf(acc[ot][3], 0.f));
      unsigned short* op = Ds + lr * DSTR + DOFF + o0 + quad*4;
      if constexpr ((DOFF & 3) == 0) {
        *(unsigned long long*)op = (unsigned long long)lo | ((unsigned long long)hi << 32);
      } else {
        *(unsigned int*)op       = lo;
        *(unsigned int*)(op + 2) = hi;
      }
    } else {
#pragma unroll
      for (int rr = 0; rr < 4; ++rr) {
        float v = fmaxf(acc[ot][rr], 0.f);
        v = fmaxf(v, __shfl_xor(v, 1, 64));
        v = fmaxf(v, __shfl_xor(v, 2, 64));
        v = fmaxf(v, __shfl_xor(v, 4, 64));
        v = fmaxf(v, __shfl_xor(v, 8, 64));
        if (lr == 0)
          atomicMax(&outmax[b * FF + o0 + quad*4 + rr], __float_as_uint(v));
      }
    }
  }
}

// ---------------- K6: fused gp chain (finalize + 4 layers + max) ----------------
// 64 blocks x 512 threads; 16 columns (one shared br) per block; activations in LDS.
__global__ __launch_bounds__(512) void k_gp(
    const unsigned int* __restrict__ pooled, const float* __restrict__ feat0,
    const int* __restrict__ rowflag, const float* __restrict__ noderot,
    const int* __restrict__ flag, const unsigned short* __restrict__ Wb,
    const void* __restrict__ gpb0, const void* __restrict__ gpb1,
    const void* __restrict__ gpb2, const void* __restrict__ gpb3,
    unsigned int* __restrict__ outmax) {
  __shared__ unsigned short G3[16 * 648];   // [j][0..129]=g_in, [130..641]=h3 (g3 input)
  __shared__ unsigned short H1[16 * 264];   // stride 264 (=132 dwords, ≡4 mod 32: conflict-free)
  __shared__ unsigned short H2[16 * 264];
  const unsigned short* gW0 = Wb + 28928;   // 256 x 130
  const unsigned short* gW1 = Wb + 62208;   // 256 x 256
  const unsigned short* gW2 = Wb + 127744;  // 512 x 256
  const unsigned short* gW3 = Wb + 258816;  // 512 x 642
  int isbf = flag[0];
  int tid = threadIdx.x, lane = tid & 63, wv = tid >> 6;   // 8 waves
  int quad = lane >> 4, lr = lane & 15;
  int c0 = blockIdx.x * 16;
  int br = c0 >> 6, b = br >> 2;
  // ---- build g_in columns (was k_finalize) ----
  {
    int j = tid >> 5, oq = (tid & 31) << 2;   // 512 threads cover 16 cols x 32 quads
    int col = c0 + j, m = col & 63;
    int fl = rowflag[b * 64 + m];
    float v[4];
#pragma unroll
    for (int i = 0; i < 4; ++i) {
      float pv = __uint_as_float(pooled[((long)col << 7) + oq + i]);
      v[i] = fl ? pv : feat0[br * 128 + oq + i];
    }
    *(unsigned int*)&G3[j * 648 + 2 + oq] = cvtpk(v[0], v[1]);
    *(unsigned int*)&G3[j * 648 + 4 + oq] = cvtpk(v[2], v[3]);
    if (tid < 32) {
      int jj = tid >> 1, o = tid & 1;
      int mm = (c0 + jj) & 63;
      G3[jj * 648 + o] = f2bf(noderot[(br * 2 + o) * 64 + mm]);
    }
  }
  __syncthreads();
  gp_layer<2, 130, 128, true,  264, 0,   0>(gW0, gpb0, isbf, G3, 648, H1, wv, quad, lr, b, outmax);
  __syncthreads();
  gp_layer<2, 256, 256, false, 264, 0,   0>(gW1, gpb1, isbf, H1, 264, H2, wv, quad, lr, b, outmax);
  __syncthreads();
  gp_layer<4, 256, 256, false, 648, 130, 0>(gW2, gpb2, isbf, H2, 264, G3, wv, quad, lr, b, outmax);
  __syncthreads();
  gp_layer<4, 642, 640, true,  0,   0,   1>(gW3, gpb3, isbf, G3, 648, nullptr, wv, quad, lr, b, outmax);
}

// ---------------- K7: output convert (dtype-adaptive) ----------------
__global__ __launch_bounds__(256) void k_out(
    const unsigned int* __restrict__ outmax, const int* __restrict__ flag,
    void* __restrict__ out) {
  int t = blockIdx.x * 256 + threadIdx.x;
  float v = __uint_as_float(outmax[t]);
  if (flag[0]) ((unsigned short*)out)[t] = f2bf(v);
  else         ((float*)out)[t] = v;
}

// ---------------- host ----------------
extern "C" void kernel_launch(void* const* d_in, const int* in_sizes, int n_in,
                              void* d_out, int out_size, void* d_ws, size_t ws_size,
                              hipStream_t stream) {
  const void* x    = d_in[0];
  const void* node = d_in[2];
  const void* fpW0 = d_in[4];  const void* fpb0 = d_in[5];
  const void* fpW1 = d_in[6];  const void* fpb1 = d_in[7];
  const void* fpW2 = d_in[8];  const void* fpb2 = d_in[9];
  const void* fpW3 = d_in[10]; const void* fpb3 = d_in[11];
  const void* gpW0 = d_in[12]; const void* gpb0 = d_in[13];
  const void* gpW1 = d_in[14]; const void* gpb1 = d_in[15];
  const void* gpW2 = d_in[16]; const void* gpb2 = d_in[17];
  const void* gpW3 = d_in[18]; const void* gpb3 = d_in[19];

  // workspace layout (~4.5 MB total; zeroed region first)
  char* ws = (char*)d_ws;
  int*            flag    = (int*)(ws + 0);              //    256 (4 used)
  float*          csum    = (float*)(ws + 256);          //   3072
  unsigned int*   outmax  = (unsigned int*)(ws + 3328);  //   8192
  unsigned int*   pooled  = (unsigned int*)(ws + 11520); // 524288
  // ---- end of memset region (535808 B) ----
  int*            idx     = (int*)(ws + 535808);         // 196608
  int*            blkcnt  = (int*)(ws + 732416);         //  16384
  float*          noderot = (float*)(ws + 766208);       //   8192
  int*            rowflag = (int*)(ws + 774400);         //   1024
  int*            sorted  = (int*)(ws + 775424);         // 196608
  float*          feat0   = (float*)(ws + 972032);       //   8192
  unsigned short* Wb      = (unsigned short*)(ws + 3355904);  // 1175040

  hipMemsetAsync(ws, 0, 535808, stream);

  WPtrs wp; wp.p[0]=fpW1; wp.p[1]=fpW2; wp.p[2]=fpW3; wp.p[3]=gpW0;
  wp.p[4]=gpW1; wp.p[5]=gpW2; wp.p[6]=gpW3;
  // merged detect + cvt + assign: blocks [0,2295) cvt, [2295,2359) assign
  k_front<<<2359, 256, 0, stream>>>(x, node, wp, flag, Wb, idx, csum, blkcnt);
  // merged means + scatter
  k_scatter2<<<64, 256, 0, stream>>>(csum, blkcnt, idx, sorted, noderot, rowflag);
  k_fused<<<dim3(48, 16), 256, 0, stream>>>(x, sorted, idx, noderot, flag,
                                            fpW0, fpb0, Wb, fpb1, fpb2, fpb3,
                                            pooled, feat0);
  // fused gp chain: finalize + 4 GEMM layers + rotation/node max
  k_gp<<<64, 512, 0, stream>>>(pooled, feat0, rowflag, noderot, flag, Wb,
                               gpb0, gpb1, gpb2, gpb3, outmax);
  k_out<<<8, 256, 0, stream>>>(outmax, flag, d_out);
}

// Round 4
// 198.679 us; speedup vs baseline: 1.3272x; 1.3272x over previous
//
#include <hip/hip_runtime.h>
#include <stdint.h>

// ---------------- problem constants ----------------
#define BB 4
#define RR 4
#define NN 4096
#define MM 64
#define KK 3
#define KNN 12288           // KK*NN
#define BRR 16              // BB*RR
#define FF 512

typedef short bf16x8 __attribute__((ext_vector_type(8)));
typedef float f32x4 __attribute__((ext_vector_type(4)));

__device__ __forceinline__ float bf2f(unsigned int u) {
  union { unsigned int i; float f; } v; v.i = u << 16; return v.f;
}
__device__ __forceinline__ unsigned short f2bf(float f) {
  union { float f; unsigned int i; } v; v.f = f;
  unsigned int x = v.i;
  return (unsigned short)((x + 0x7fffu + ((x >> 16) & 1u)) >> 16);
}
// packed RNE f32x2 -> bf16x2 (T12 recipe; no builtin on gfx950)
__device__ __forceinline__ unsigned int cvtpk(float a, float b) {
  unsigned int r;
  asm("v_cvt_pk_bf16_f32 %0, %1, %2" : "=v"(r) : "v"(a), "v"(b));
  return r;
}
// dtype-adaptive load: isbf=1 -> buffer is bf16 ushorts; else fp32 floats
__device__ __forceinline__ float ldf(const void* p, long i, int isbf) {
  if (isbf) return bf2f(((const unsigned short*)p)[i]);
  return ((const float*)p)[i];
}
// LDS bank-conflict swizzles (XOR short-offset bits 3..4 with col bits 3..4).
__device__ __forceinline__ int hsw(int col, int so) { return col * 72  + (so ^ (col & 24)); }
__device__ __forceinline__ int csw(int col, int so) { return col * 168 + (so ^ (col & 24)); } // so < 160

struct WPtrs { const void* p[16]; };
// 0..6: fpW1,fpW2,fpW3,gpW0,gpW1,gpW2,gpW3 (-> Wb bf16)
// 7..15: fpW0,fpb0,fpb1,fpb2,fpb3,gpb0,gpb1,gpb2,gpb3 (-> Fb f32)
// Fb float layout: fW0@0(128) fb0@128(64) fb1@192(64) fb2@256(128) fb3@384(128)
//                  gpb0@512(256) gpb1@768(256) gpb2@1024(512) gpb3@1536(512)

// ---------------- K0: merged dtype-probe + weight-cvt + assign ----------------
// blocks [0,2383): canonicalize weights (Wb bf16, fW3p padded-K160, Fb f32)
// blocks [2383,2447): top-3 assignment + cluster sums + per-block histogram
__global__ __launch_bounds__(256) void k_front(
    const void* __restrict__ x, const void* __restrict__ node, WPtrs wp,
    int* __restrict__ flag, unsigned short* __restrict__ Wb,
    unsigned short* __restrict__ fW3p, float* __restrict__ Fb,
    int* __restrict__ idx, float* __restrict__ csum, int* __restrict__ blkcnt) {
  __shared__ int bad;
  __shared__ float nd[2][64];
  __shared__ float cs[192];   // [m][{sx,sy,cnt}]
  int tid = threadIdx.x;
  if (tid == 0) bad = 0;
  __syncthreads();
  {
    const unsigned short* xs = (const unsigned short*)x;
    int cnt = 0;
    for (int i = tid; i < 1024; i += 256) {
      unsigned short u = xs[i * 2];
      int e = (u >> 7) & 0xFF;
      if (e >= 0x90 || (e > 0 && e <= 0x50)) ++cnt;
    }
    atomicAdd(&bad, cnt);
  }
  __syncthreads();
  int isbf = (bad < 100) ? 1 : 0;
  if (blockIdx.x == 0 && tid == 0) flag[0] = isbf;

  if (blockIdx.x < 2383) {
    const int e0=4096, e1=12288, e2=28928, e3=62208, e4=127744, e5=258816, e6=587520;
    int t = blockIdx.x * 256 + tid;
    if (t < e6) {
      // ---- main bf16 weight canonicalization ----
      int s, base;
      if      (t < e0) { s=0; base=0;  }
      else if (t < e1) { s=1; base=e0; }
      else if (t < e2) { s=2; base=e1; }
      else if (t < e3) { s=3; base=e2; }
      else if (t < e4) { s=4; base=e3; }
      else if (t < e5) { s=5; base=e4; }
      else             { s=6; base=e5; }
      int local = t - base;
      unsigned short u;
      if (isbf) u = ((const unsigned short*)wp.p[s])[local];
      else      u = f2bf(((const float*)wp.p[s])[local]);
      Wb[t] = u;
    } else if (t < 608000) {
      // ---- fW3 zero-padded to 128 x 160 ----
      int l = t - e6;
      int o = l / 160, c = l - o * 160;
      unsigned short u = 0;
      if (c < 130) {
        long si = (long)o * 130 + c;
        if (isbf) u = ((const unsigned short*)wp.p[2])[si];
        else      u = f2bf(((const float*)wp.p[2])[si]);
      }
      fW3p[l] = u;
    } else if (t < 610048) {
      // ---- f32 table: fW0 + all biases (numerics-preserving) ----
      int l = t - 608000;
      const void* src; int off;
      if      (l < 128)  { src = wp.p[7];  off = 0;    }
      else if (l < 192)  { src = wp.p[8];  off = 128;  }
      else if (l < 256)  { src = wp.p[9];  off = 192;  }
      else if (l < 384)  { src = wp.p[10]; off = 256;  }
      else if (l < 512)  { src = wp.p[11]; off = 384;  }
      else if (l < 768)  { src = wp.p[12]; off = 512;  }
      else if (l < 1024) { src = wp.p[13]; off = 768;  }
      else if (l < 1536) { src = wp.p[14]; off = 1024; }
      else               { src = wp.p[15]; off = 1536; }
      Fb[l] = ldf(src, l - off, isbf);
    }
    return;
  }
  // ---- assign ----
  int bi = blockIdx.x - 2383;        // b*16 + chunk
  int b = bi >> 4;
  int n = ((bi & 15) << 8) + tid;
  if (tid < 128) nd[tid >> 6][tid & 63] = ldf(node, b * 128 + tid, isbf);
  if (tid < 192) cs[tid] = 0.f;
  __syncthreads();
  float x0 = ldf(x, b * 8192 + n, isbf);
  float x1 = ldf(x, b * 8192 + 4096 + n, isbf);
  float d0 = 1e30f, d1 = 1e30f, d2 = 1e30f;
  int m0 = 0, m1 = 0, m2 = 0;
#pragma unroll 8
  for (int m = 0; m < 64; ++m) {
    float dx = x0 - nd[0][m];
    float dy = x1 - nd[1][m];
    float d = __fmul_rn(dx, dx) + __fmul_rn(dy, dy);   // no contraction: match ref
    if (d < d0)      { d2=d1; m2=m1; d1=d0; m1=m0; d0=d; m0=m; }
    else if (d < d1) { d2=d1; m2=m1; d1=d;  m1=m; }
    else if (d < d2) { d2=d;  m2=m; }
  }
  long base = ((long)b * NN + n) * 3;
  idx[base] = m0; idx[base + 1] = m1; idx[base + 2] = m2;
  atomicAdd(&cs[m0*3+0], x0); atomicAdd(&cs[m0*3+1], x1); atomicAdd(&cs[m0*3+2], 1.f);
  atomicAdd(&cs[m1*3+0], x0); atomicAdd(&cs[m1*3+1], x1); atomicAdd(&cs[m1*3+2], 1.f);
  atomicAdd(&cs[m2*3+0], x0); atomicAdd(&cs[m2*3+1], x1); atomicAdd(&cs[m2*3+2], 1.f);
  __syncthreads();
  if (tid < 192) atomicAdd(&csum[b * 192 + tid], cs[tid]);
  if (tid < 64) blkcnt[bi * 64 + tid] = (int)cs[tid*3 + 2];
}

// ---------------- K1: merged means + counting-sort scatter ----------------
__global__ __launch_bounds__(256) void k_scatter2(
    const float* __restrict__ csum, const int* __restrict__ blkcnt,
    const int* __restrict__ idx, int* __restrict__ sorted,
    float* __restrict__ noderot, int* __restrict__ rowflag) {
  __shared__ int scnt[64];
  __shared__ int soff[64];
  __shared__ int lc[64];
  int tid = threadIdx.x;
  int blk = blockIdx.x;              // b*16 + chunk (matches k_front assign)
  int b = blk >> 4, chunk = blk & 15;
  if (tid < 64) scnt[tid] = (int)csum[b*192 + tid*3 + 2];
  __syncthreads();
  if (tid < 64) {
    int m = tid, acc = 0;
    for (int mm = 0; mm < m; ++mm) acc += scnt[mm];          // counts are exact floats
    for (int c = 0; c < chunk; ++c) acc += blkcnt[(b*16 + c)*64 + m];
    soff[m] = acc;
    lc[m] = 0;
    if (chunk == 0) {
      float s0 = csum[b*192 + m*3], s1 = csum[b*192 + m*3 + 1], cc = csum[b*192 + m*3 + 2];
      float mx = s0 / (cc + 1e-5f);
      float my = s1 / (cc + 1e-5f);
      rowflag[b*64 + m] = (cc > 0.f) ? 1 : 0;
      for (int r = 0; r < 4; ++r) {
        float th = 1.5707964f * (float)r;
        float cr = cosf(th), sr = sinf(th);
        noderot[((b*4 + r)*2 + 0)*64 + m] = cr*mx - sr*my;
        noderot[((b*4 + r)*2 + 1)*64 + m] = sr*mx + cr*my;
      }
    }
  }
  __syncthreads();
  int n = ((blk & 15) << 8) + tid;
#pragma unroll
  for (int kk = 0; kk < 3; ++kk) {
    int m = idx[((long)b * NN + n) * 3 + kk];
    int pos = atomicAdd(&lc[m], 1);                 // LDS atomic, order irrelevant
    sorted[b * KNN + soff[m] + pos] = (m << 12) | n;
  }
}

// ---------------- K5: fused fp block (r1 structure + VALU cuts) ----------------
// grid (192, 16). Occupancy-first: no weight hoisting, low VGPR. VALU cuts:
// f32 bias/fW0 table (no dtype branches), padded-K160 layer3 (no scalar tail),
// integer-max packed scan (16 iters).
__global__ __launch_bounds__(256) void k_fused(
    const void* __restrict__ x, const int* __restrict__ sorted,
    const int* __restrict__ idx, const float* __restrict__ noderot,
    const int* __restrict__ flag, const unsigned short* __restrict__ Wb,
    const unsigned short* __restrict__ fW3p, const float* __restrict__ Fb,
    unsigned int* __restrict__ pooled, float* __restrict__ feat0) {
  __shared__ unsigned short Cs[64 * 168];   // [col][0..1]=xdec,[2..129]=h2,[130..159]=0; later [0..127]=feat
  __shared__ unsigned short Hs[64 * 72];    // h1
  __shared__ int mcol[64];                  // m | (is_col0 << 8)
  const unsigned short* fW1 = Wb;           // 64x64
  const unsigned short* fW2 = Wb + 4096;    // 128x64
  int isbf = flag[0];
  int tid = threadIdx.x, lane = tid & 63, wv = tid >> 6;
  int quad = lane >> 4, lr = lane & 15;
  int br = blockIdx.y, b = br >> 2, r = br & 3;
  int o1 = wv * 16;
  if (tid < 64) {
    int e = sorted[b * KNN + blockIdx.x * 64 + tid];
    int m = e >> 12, n = e & 4095;
    int isz = (n == 0 && m == idx[(long)b * NN * 3]) ? 256 : 0;
    mcol[tid] = m | isz;
    float x0 = ldf(x, b*8192 + n, isbf), x1 = ldf(x, b*8192 + 4096 + n, isbf);
    float th = 1.5707964f * (float)r;
    float cr = cosf(th), sr = sinf(th);
    float xd0 = (cr*x0 - sr*x1) - noderot[(br*2 + 0)*64 + m];
    float xd1 = (sr*x0 + cr*x1) - noderot[(br*2 + 1)*64 + m];
    *(unsigned int*)&Cs[csw(tid, 0)] = cvtpk(xd0, xd1);
  }
  // zero logical channels 130..159 (once per block; never overwritten)
  for (int z = tid; z < 960; z += 256) {
    int col = z / 15, l = 130 + (z - col * 15) * 2;
    *(unsigned int*)&Cs[csw(col, l)] = 0u;
  }
  __syncthreads();
  // ----- layer0 (2 -> 64), VALU, weights/bias from f32 table -----
  {
    int col = tid & 63, og = (tid >> 6) << 4;
    unsigned int xu = *(unsigned int*)&Cs[csw(col, 0)];
    float fx0 = bf2f(xu & 0xffff), fx1 = bf2f(xu >> 16);
    const float2* w2 = (const float2*)Fb;
    float hv[16];
#pragma unroll
    for (int j = 0; j < 16; ++j) {
      int o = og + j;
      float2 w = w2[o];
      float h = Fb[128 + o] + w.x * fx0 + w.y * fx1;
      hv[j] = fmaxf(h, 0.f);
    }
    union { bf16x8 v; unsigned int u[4]; } o8[2];
#pragma unroll
    for (int j = 0; j < 16; j += 2) o8[j >> 3].u[(j & 7) >> 1] = cvtpk(hv[j], hv[j+1]);
    *(bf16x8*)&Hs[hsw(col, og)]     = o8[0].v;
    *(bf16x8*)&Hs[hsw(col, og + 8)] = o8[1].v;
  }
  __syncthreads();
  // ----- layer1 (64 -> 64), MFMA -----
  {
    f32x4 acc[4];
#pragma unroll
    for (int nt = 0; nt < 4; ++nt)
      acc[nt] = (f32x4){Fb[192 + o1 + quad*4], Fb[192 + o1 + quad*4 + 1],
                        Fb[192 + o1 + quad*4 + 2], Fb[192 + o1 + quad*4 + 3]};
#pragma unroll
    for (int ks2 = 0; ks2 < 2; ++ks2) {
      bf16x8 a = *(const bf16x8*)(fW1 + (o1 + lr)*64 + ks2*32 + quad*8);
#pragma unroll
      for (int nt = 0; nt < 4; ++nt) {
        bf16x8 bf = *(bf16x8*)&Hs[hsw(nt*16 + lr, ks2*32 + quad*8)];
        acc[nt] = __builtin_amdgcn_mfma_f32_16x16x32_bf16(a, bf, acc[nt], 0, 0, 0);
      }
    }
    __syncthreads();  // everyone done READING Hs
#pragma unroll
    for (int nt = 0; nt < 4; ++nt) {
      int col = nt*16 + lr;
      unsigned int lo = cvtpk(fmaxf(acc[nt][0], 0.f), fmaxf(acc[nt][1], 0.f));
      unsigned int hi = cvtpk(fmaxf(acc[nt][2], 0.f), fmaxf(acc[nt][3], 0.f));
      *(unsigned long long*)&Hs[hsw(col, o1 + quad*4)] =
          (unsigned long long)lo | ((unsigned long long)hi << 32);
    }
  }
  __syncthreads();
  // ----- layer2 (64 -> 128), MFMA, output into Cs logical [2..129] -----
#pragma unroll
  for (int p2 = 0; p2 < 2; ++p2) {
    int o0 = p2*64 + o1;
    f32x4 acc[4];
#pragma unroll
    for (int nt = 0; nt < 4; ++nt)
      acc[nt] = (f32x4){Fb[256 + o0 + quad*4], Fb[256 + o0 + quad*4 + 1],
                        Fb[256 + o0 + quad*4 + 2], Fb[256 + o0 + quad*4 + 3]};
#pragma unroll
    for (int ks2 = 0; ks2 < 2; ++ks2) {
      bf16x8 a = *(const bf16x8*)(fW2 + (o0 + lr)*64 + ks2*32 + quad*8);
#pragma unroll
      for (int nt = 0; nt < 4; ++nt) {
        bf16x8 bf = *(bf16x8*)&Hs[hsw(nt*16 + lr, ks2*32 + quad*8)];
        acc[nt] = __builtin_amdgcn_mfma_f32_16x16x32_bf16(a, bf, acc[nt], 0, 0, 0);
      }
    }
#pragma unroll
    for (int nt = 0; nt < 4; ++nt) {
      int col = nt*16 + lr;
      int o = o0 + quad*4;
      unsigned int w0 = cvtpk(fmaxf(acc[nt][0], 0.f), fmaxf(acc[nt][1], 0.f));
      unsigned int w1 = cvtpk(fmaxf(acc[nt][2], 0.f), fmaxf(acc[nt][3], 0.f));
      *(unsigned int*)&Cs[csw(col, 2 + o)] = w0;
      *(unsigned int*)&Cs[csw(col, 4 + o)] = w1;
    }
  }
  __syncthreads();
  // ----- layer3 (K padded to 160): 5 clean MFMA steps, no scalar tail -----
  f32x4 acc3[2][4];
#pragma unroll
  for (int p3 = 0; p3 < 2; ++p3) {
    int o0 = p3*64 + o1;
#pragma unroll
    for (int nt = 0; nt < 4; ++nt)
      acc3[p3][nt] = (f32x4){Fb[384 + o0 + quad*4], Fb[384 + o0 + quad*4 + 1],
                             Fb[384 + o0 + quad*4 + 2], Fb[384 + o0 + quad*4 + 3]};
#pragma unroll
    for (int ks5 = 0; ks5 < 5; ++ks5) {
      bf16x8 a = *(const bf16x8*)(fW3p + (o0 + lr)*160 + ks5*32 + quad*8);
#pragma unroll
      for (int nt = 0; nt < 4; ++nt) {
        bf16x8 bf = *(bf16x8*)&Cs[csw(nt*16 + lr, ks5*32 + quad*8)];
        acc3[p3][nt] = __builtin_amdgcn_mfma_f32_16x16x32_bf16(a, bf, acc3[p3][nt], 0, 0, 0);
      }
    }
  }
  __syncthreads();   // ALL Cs reads complete before feat overwrite
#pragma unroll
  for (int p3 = 0; p3 < 2; ++p3) {
    int o0 = p3*64 + o1;
#pragma unroll
    for (int nt = 0; nt < 4; ++nt) {
      int col = nt*16 + lr;
      unsigned int lo = cvtpk(fmaxf(acc3[p3][nt][0], 0.f), fmaxf(acc3[p3][nt][1], 0.f));
      unsigned int hi = cvtpk(fmaxf(acc3[p3][nt][2], 0.f), fmaxf(acc3[p3][nt][3], 0.f));
      *(unsigned long long*)&Cs[csw(col, o0 + quad*4)] =
          (unsigned long long)lo | ((unsigned long long)hi << 32);
    }
  }
  __syncthreads();
  // ----- run-scan segment max: packed u32, integer max (bf16>=0 => u16 order) ---
  {
    int opair = tid & 63, h = tid >> 6;      // wave-uniform h: 4 waves x 16 cols
    int o0 = opair * 2;
    int c0 = h * 16;
    int curm = mcol[c0] & 255;
    unsigned int vlo = 0u, vhi = 0u;
    for (int c = c0; c < c0 + 16; ++c) {
      int mc = mcol[c];
      int mm = mc & 255;
      unsigned int u = *(unsigned int*)&Cs[csw(c, o0)];
      if (mm != curm) {
        atomicMax(&pooled[(((long)br*64 + curm) << 7) + o0],     vlo);
        atomicMax(&pooled[(((long)br*64 + curm) << 7) + o0 + 1], vhi);
        curm = mm; vlo = vhi = 0u;
      }
      vlo = max(vlo, u << 16);
      vhi = max(vhi, u & 0xffff0000u);
      if (mc & 256) {
        feat0[br*128 + o0]     = __uint_as_float(u << 16);
        feat0[br*128 + o0 + 1] = __uint_as_float(u & 0xffff0000u);
      }
    }
    atomicMax(&pooled[(((long)br*64 + curm) << 7) + o0],     vlo);
    atomicMax(&pooled[(((long)br*64 + curm) << 7) + o0 + 1], vhi);
  }
}

// ---------------- gp layer helper (per-wave; ot inside ks for load pipelining) --
template<int OT, int KW, int KMAIN, bool REM2, int DSTR, int DOFF, int EPI>
__device__ __forceinline__ void gp_layer(
    const unsigned short* __restrict__ W, const float* __restrict__ bias,
    const unsigned short* Bs, int bstr, unsigned short* Ds,
    int wv, int quad, int lr, int b, unsigned int* __restrict__ outmax) {
  f32x4 acc[OT];
#pragma unroll
  for (int ot = 0; ot < OT; ++ot) {
    int o0 = (wv * OT + ot) * 16;
    acc[ot] = (f32x4){bias[o0 + quad*4], bias[o0 + quad*4 + 1],
                      bias[o0 + quad*4 + 2], bias[o0 + quad*4 + 3]};
  }
  const unsigned short* brow = Bs + lr * bstr;
  for (int ks = 0; ks < KMAIN; ks += 32) {
    bf16x8 bf = *(const bf16x8*)(brow + ks + quad*8);
    bf16x8 a[OT];
#pragma unroll
    for (int ot = 0; ot < OT; ++ot) {
      const unsigned short* arow = W + (long)((wv * OT + ot) * 16 + lr) * KW;
      if constexpr ((KW % 8) == 0) {
        a[ot] = *(const bf16x8*)(arow + ks + quad*8);
      } else {
        union { bf16x8 v; unsigned int u[4]; } au;
        const unsigned int* ap = (const unsigned int*)(arow + ks + quad*8);  // 4B aligned
        au.u[0] = ap[0]; au.u[1] = ap[1]; au.u[2] = ap[2]; au.u[3] = ap[3];
        a[ot] = au.v;
      }
    }
#pragma unroll
    for (int ot = 0; ot < OT; ++ot)
      acc[ot] = __builtin_amdgcn_mfma_f32_16x16x32_bf16(a[ot], bf, acc[ot], 0, 0, 0);
  }
  if constexpr (REM2) {
    unsigned int bu = *(const unsigned int*)(brow + KMAIN);
    float b0 = bf2f(bu & 0xffff), b1 = bf2f(bu >> 16);
#pragma unroll
    for (int ot = 0; ot < OT; ++ot) {
#pragma unroll
      for (int rr = 0; rr < 4; ++rr) {
        int o = (wv * OT + ot) * 16 + quad*4 + rr;
        unsigned int wu = *(const unsigned int*)(W + (long)o * KW + KMAIN);
        acc[ot][rr] += bf2f(wu & 0xffff) * b0 + bf2f(wu >> 16) * b1;
      }
    }
  }
#pragma unroll
  for (int ot = 0; ot < OT; ++ot) {
    int o0 = (wv * OT + ot) * 16;
    if constexpr (EPI == 0) {
      unsigned int lo = cvtpk(fmaxf(acc[ot][0], 0.f), fmaxf(acc[ot][1], 0.f));
      unsigned int hi = cvtpk(fmaxf(acc[ot][2], 0.f), fmaxf(acc[ot][3], 0.f));
      unsigned short* op = Ds + lr * DSTR + DOFF + o0 + quad*4;
      if constexpr ((DOFF & 3) == 0) {
        *(unsigned long long*)op = (unsigned long long)lo | ((unsigned long long)hi << 32);
      } else {
        *(unsigned int*)op       = lo;
        *(unsigned int*)(op + 2) = hi;
      }
    } else {
#pragma unroll
      for (int rr = 0; rr < 4; ++rr) {
        float v = fmaxf(acc[ot][rr], 0.f);
        v = fmaxf(v, __shfl_xor(v, 1, 64));
        v = fmaxf(v, __shfl_xor(v, 2, 64));
        v = fmaxf(v, __shfl_xor(v, 4, 64));
        v = fmaxf(v, __shfl_xor(v, 8, 64));
        if (lr == 0)
          atomicMax(&outmax[b * FF + o0 + quad*4 + rr], __float_as_uint(v));
      }
    }
  }
}

// ---------------- K6: fused gp chain, 1024 threads (16 waves, halved chain) ----
__global__ __launch_bounds__(1024) void k_gp(
    const unsigned int* __restrict__ pooled, const float* __restrict__ feat0,
    const int* __restrict__ rowflag, const float* __restrict__ noderot,
    const unsigned short* __restrict__ Wb, const float* __restrict__ Fb,
    unsigned int* __restrict__ outmax) {
  __shared__ unsigned short G3[16 * 648];   // [j][0..129]=g_in, [130..641]=h3
  __shared__ unsigned short H1[16 * 264];   // stride 264: 132 dw == 4 mod 32
  __shared__ unsigned short H2[16 * 264];
  const unsigned short* gW0 = Wb + 28928;   // 256 x 130
  const unsigned short* gW1 = Wb + 62208;   // 256 x 256
  const unsigned short* gW2 = Wb + 127744;  // 512 x 256
  const unsigned short* gW3 = Wb + 258816;  // 512 x 642
  int tid = threadIdx.x, lane = tid & 63, wv = tid >> 6;   // 16 waves
  int quad = lane >> 4, lr = lane & 15;
  int c0 = blockIdx.x * 16;
  int br = c0 >> 6, b = br >> 2;
  // ---- build g_in columns ----
  {
    int j = tid >> 6, oq = (tid & 63) << 1;   // 16 cols x 64 thr, 2 o's each
    int col = c0 + j, m = col & 63;
    int fl = rowflag[b * 64 + m];
    float v0 = __uint_as_float(pooled[((long)col << 7) + oq]);
    float v1 = __uint_as_float(pooled[((long)col << 7) + oq + 1]);
    if (!fl) { v0 = feat0[br * 128 + oq]; v1 = feat0[br * 128 + oq + 1]; }
    *(unsigned int*)&G3[j * 648 + 2 + oq] = cvtpk(v0, v1);
    if (tid < 32) {
      int jj = tid >> 1, o = tid & 1;
      int mm = (c0 + jj) & 63;
      G3[jj * 648 + o] = f2bf(noderot[(br * 2 + o) * 64 + mm]);
    }
  }
  __syncthreads();
  gp_layer<1, 130, 128, true,  264, 0,   0>(gW0, Fb + 512,  G3, 648, H1, wv, quad, lr, b, outmax);
  __syncthreads();
  gp_layer<1, 256, 256, false, 264, 0,   0>(gW1, Fb + 768,  H1, 264, H2, wv, quad, lr, b, outmax);
  __syncthreads();
  gp_layer<2, 256, 256, false, 648, 130, 0>(gW2, Fb + 1024, H2, 264, G3, wv, quad, lr, b, outmax);
  __syncthreads();
  gp_layer<2, 642, 640, true,  0,   0,   1>(gW3, Fb + 1536, G3, 648, nullptr, wv, quad, lr, b, outmax);
}

// ---------------- K7: output convert (dtype-adaptive) ----------------
__global__ __launch_bounds__(256) void k_out(
    const unsigned int* __restrict__ outmax, const int* __restrict__ flag,
    void* __restrict__ out) {
  int t = blockIdx.x * 256 + threadIdx.x;
  float v = __uint_as_float(outmax[t]);
  if (flag[0]) ((unsigned short*)out)[t] = f2bf(v);
  else         ((float*)out)[t] = v;
}

// ---------------- host ----------------
extern "C" void kernel_launch(void* const* d_in, const int* in_sizes, int n_in,
                              void* d_out, int out_size, void* d_ws, size_t ws_size,
                              hipStream_t stream) {
  const void* x    = d_in[0];
  const void* node = d_in[2];

  // workspace layout (zeroed region first)
  char* ws = (char*)d_ws;
  int*            flag    = (int*)(ws + 0);              //    256 (4 used)
  float*          csum    = (float*)(ws + 256);          //   3072
  unsigned int*   outmax  = (unsigned int*)(ws + 3328);  //   8192
  unsigned int*   pooled  = (unsigned int*)(ws + 11520); // 524288
  // ---- end of memset region (535808 B) ----
  int*            idx     = (int*)(ws + 535808);         // 196608
  int*            blkcnt  = (int*)(ws + 732416);         //  16384
  float*          noderot = (float*)(ws + 766208);       //   8192
  int*            rowflag = (int*)(ws + 774400);         //   1024
  int*            sorted  = (int*)(ws + 775424);         // 196608
  float*          feat0   = (float*)(ws + 972032);       //   8192
  unsigned short* fW3p    = (unsigned short*)(ws + 980224);   // 40960 (128x160 bf16)
  float*          Fb      = (float*)(ws + 1021184);      //   8192 (2048 f32)
  unsigned short* Wb      = (unsigned short*)(ws + 3355904);  // 1175040

  hipMemsetAsync(ws, 0, 535808, stream);

  WPtrs wp;
  wp.p[0]=d_in[6];  wp.p[1]=d_in[8];  wp.p[2]=d_in[10];             // fpW1,fpW2,fpW3
  wp.p[3]=d_in[12]; wp.p[4]=d_in[14]; wp.p[5]=d_in[16]; wp.p[6]=d_in[18]; // gpW0..3
  wp.p[7]=d_in[4];                                                   // fpW0
  wp.p[8]=d_in[5];  wp.p[9]=d_in[7];  wp.p[10]=d_in[9]; wp.p[11]=d_in[11]; // fpb0..3
  wp.p[12]=d_in[13]; wp.p[13]=d_in[15]; wp.p[14]=d_in[17]; wp.p[15]=d_in[19]; // gpb0..3

  // merged detect + cvt + assign: blocks [0,2383) cvt, [2383,2447) assign
  k_front<<<2447, 256, 0, stream>>>(x, node, wp, flag, Wb, fW3p, Fb, idx, csum, blkcnt);
  // merged means + scatter
  k_scatter2<<<64, 256, 0, stream>>>(csum, blkcnt, idx, sorted, noderot, rowflag);
  k_fused<<<dim3(192, 16), 256, 0, stream>>>(x, sorted, idx, noderot, flag,
                                             Wb, fW3p, Fb, pooled, feat0);
  // fused gp chain: finalize + 4 GEMM layers + rotation/node max
  k_gp<<<64, 1024, 0, stream>>>(pooled, feat0, rowflag, noderot, Wb, Fb, outmax);
  k_out<<<8, 256, 0, stream>>>(outmax, flag, d_out);
}